// Round 1
// baseline (157.012 us; speedup 1.0000x reference)
//
#include <hip/hip_runtime.h>
#include <math.h>

#define S_LEN 2048
#define D_MODEL 512
#define NIMU 13
#define NPAR 9
#define NCOL 117           // 13*9
#define WS_NCOLP 128       // padded LDS cols for W tile

static __device__ __forceinline__ float softplus_f(float x) {
    return (x > 20.f) ? x : log1pf(expf(x));
}

// ---------------- kernel 1: per-row layernorm stats ----------------
__global__ __launch_bounds__(256) void stats_kernel(const float* __restrict__ H,
                                                    float2* __restrict__ stats) {
    int wave = threadIdx.x >> 6;
    int lane = threadIdx.x & 63;
    int row = blockIdx.x * 4 + wave;
    if (row >= S_LEN) return;
    const float* hr = H + row * D_MODEL;
    float4 a = *(const float4*)&hr[lane * 4];
    float4 b = *(const float4*)&hr[256 + lane * 4];
    float sum = a.x + a.y + a.z + a.w + b.x + b.y + b.z + b.w;
    #pragma unroll
    for (int off = 32; off; off >>= 1) sum += __shfl_down(sum, off);
    sum = __shfl(sum, 0);
    float mu = sum * (1.f / 512.f);
    float vs = 0.f;
    vs += (a.x - mu) * (a.x - mu); vs += (a.y - mu) * (a.y - mu);
    vs += (a.z - mu) * (a.z - mu); vs += (a.w - mu) * (a.w - mu);
    vs += (b.x - mu) * (b.x - mu); vs += (b.y - mu) * (b.y - mu);
    vs += (b.z - mu) * (b.z - mu); vs += (b.w - mu) * (b.w - mu);
    #pragma unroll
    for (int off = 32; off; off >>= 1) vs += __shfl_down(vs, off);
    if (lane == 0) {
        float var = vs * (1.f / 512.f);
        float rstd = 1.0f / sqrtf(var + 1e-5f);
        stats[row] = make_float2(mu, rstd);
    }
}

// ---------------- kernel 2: projection GEMM (K-split, atomic partials) ----------------
// block: 256 threads; grid (32 row-tiles of 64, 8 k-chunks of 64)
__global__ __launch_bounds__(256) void proj_kernel(
    const float* __restrict__ H, const float2* __restrict__ stats,
    const float* __restrict__ lnw, const float* __restrict__ lnb,
    const float* __restrict__ W, float* __restrict__ P)
{
    __shared__ float Xs[64][64];         // [row][k]
    __shared__ float Ws[64][WS_NCOLP];   // [k][col], zero-padded cols
    int tid = threadIdx.x;
    int row0 = blockIdx.x * 64;
    int k0 = blockIdx.y * 64;

    {   // stage normalized X tile
        int kg = tid & 15, r0 = tid >> 4;
        for (int r = r0; r < 64; r += 16) {
            int row = row0 + r;
            float2 st = stats[row];
            float4 h4 = *(const float4*)&H[row * D_MODEL + k0 + kg * 4];
            float4 wv = *(const float4*)&lnw[k0 + kg * 4];
            float4 bv = *(const float4*)&lnb[k0 + kg * 4];
            Xs[r][kg * 4 + 0] = (h4.x - st.x) * st.y * wv.x + bv.x;
            Xs[r][kg * 4 + 1] = (h4.y - st.x) * st.y * wv.y + bv.y;
            Xs[r][kg * 4 + 2] = (h4.z - st.x) * st.y * wv.z + bv.z;
            Xs[r][kg * 4 + 3] = (h4.w - st.x) * st.y * wv.w + bv.w;
        }
    }
    // stage W tile (pad cols >= 117 with zeros)
    for (int idx = tid; idx < 64 * WS_NCOLP; idx += 256) {
        int k = idx >> 7;
        int c = idx & (WS_NCOLP - 1);
        Ws[k][c] = (c < NCOL) ? W[(k0 + k) * NCOL + c] : 0.f;
    }
    __syncthreads();

    int cg = tid & 31;   // cols cg*4 .. cg*4+3
    int rr = tid >> 5;   // rows rr + 8*g
    float acc[8][4];
    #pragma unroll
    for (int g = 0; g < 8; ++g)
        for (int q = 0; q < 4; ++q) acc[g][q] = 0.f;

    for (int kb = 0; kb < 16; ++kb) {
        float4 w0 = *(float4*)&Ws[kb * 4 + 0][cg * 4];
        float4 w1 = *(float4*)&Ws[kb * 4 + 1][cg * 4];
        float4 w2 = *(float4*)&Ws[kb * 4 + 2][cg * 4];
        float4 w3 = *(float4*)&Ws[kb * 4 + 3][cg * 4];
        #pragma unroll
        for (int g = 0; g < 8; ++g) {
            float4 a = *(float4*)&Xs[rr + 8 * g][kb * 4];
            acc[g][0] = fmaf(a.w, w3.x, fmaf(a.z, w2.x, fmaf(a.y, w1.x, fmaf(a.x, w0.x, acc[g][0]))));
            acc[g][1] = fmaf(a.w, w3.y, fmaf(a.z, w2.y, fmaf(a.y, w1.y, fmaf(a.x, w0.y, acc[g][1]))));
            acc[g][2] = fmaf(a.w, w3.z, fmaf(a.z, w2.z, fmaf(a.y, w1.z, fmaf(a.x, w0.z, acc[g][2]))));
            acc[g][3] = fmaf(a.w, w3.w, fmaf(a.z, w2.w, fmaf(a.y, w1.w, fmaf(a.x, w0.w, acc[g][3]))));
        }
    }
    for (int g = 0; g < 8; ++g) {
        int row = row0 + rr + 8 * g;
        #pragma unroll
        for (int q = 0; q < 4; ++q) {
            int c = cg * 4 + q;
            if (c < NCOL) atomicAdd(&P[row * NCOL + c], acc[g][q]);
        }
    }
}

// ---------------- kernel 3: param transform + output init ----------------
__global__ __launch_bounds__(256) void transform_kernel(
    const float* __restrict__ P, const float* __restrict__ bias,
    const float* __restrict__ minp,
    float4* __restrict__ PARL, float4* __restrict__ PARA,
    float* __restrict__ out)
{
    int t = blockIdx.x * 256 + threadIdx.x;
    if (t >= S_LEN * NIMU) return;
    int s = t / NIMU;
    int m = t - s * NIMU;
    float pv[9];
    #pragma unroll
    for (int pp = 0; pp < 9; ++pp)
        pv[pp] = P[s * NCOL + pp * NIMU + m] + bias[pp * NIMU + m];

    const float LOG2E = 1.4426950408889634f;
    const float INV2PI = 0.15915494309189535f;
    {   // linear oscillator: p1 -> d, p0 -> k, amplitude p4, phase p6
        float d = sqrtf(pv[1] * pv[1] + 1e-5f);
        float kk = d * d * 0.25f + softplus_f(pv[0]);
        float om = 0.5f * sqrtf(fmaxf(4.f * kk - d * d, 0.f));
        PARL[m * S_LEN + s] = make_float4(pv[4], -0.5f * d * LOG2E, om * INV2PI, pv[6] * INV2PI);
    }
    {   // angular oscillator: p3 -> d_th, p2 -> k_th, amplitude p5, phase p7
        float d = sqrtf(pv[3] * pv[3] + 1e-5f);
        float kk = d * d * 0.25f + softplus_f(pv[2]);
        float om = 0.5f * sqrtf(fmaxf(4.f * kk - d * d, 0.f));
        PARA[m * S_LEN + s] = make_float4(pv[5], -0.5f * d * LOG2E, om * INV2PI, pv[7] * INV2PI);
    }
    out[m * S_LEN + s] = minp[0] + pv[8];
}

// ---------------- kernel 4: triangular damped-sinusoid sum ----------------
// grid: (j-tile 8, i-chunk 8, m 13); block 256 (one j per thread)
__global__ __launch_bounds__(256) void main_kernel(
    const float4* __restrict__ PARL, const float4* __restrict__ PARA,
    float* __restrict__ out)
{
    int jt = blockIdx.x, ic = blockIdx.y, m = blockIdx.z;
    if (ic > jt) return;   // tile entirely below diagonal
    __shared__ float4 PL[256];
    __shared__ float4 PA[256];
    int tid = threadIdx.x;
    int i0 = ic * 256;
    PL[tid] = PARL[m * S_LEN + i0 + tid];
    PA[tid] = PARA[m * S_LEN + i0 + tid];
    __syncthreads();

    int j = jt * 256 + tid;
    float jf = (float)j;
    float acc = 0.f;
    int iimax = min(255, j - i0);   // j >= i0 guaranteed since jt >= ic
    for (int ii = 0; ii <= iimax; ++ii) {
        float dtf = jf - (float)(i0 + ii);
        float4 pl = PL[ii];
        float e1 = __builtin_amdgcn_exp2f(dtf * pl.y);
        float r1 = fmaf(dtf, pl.z, pl.w);
        r1 -= floorf(r1);
        float s1 = __builtin_amdgcn_sinf(r1);   // v_sin: sin(2*pi*r)
        acc = fmaf(pl.x * e1, s1, acc);
        float4 pa = PA[ii];
        float e2 = __builtin_amdgcn_exp2f(dtf * pa.y);
        float r2 = fmaf(dtf, pa.z, pa.w);
        r2 -= floorf(r2);
        float s2 = __builtin_amdgcn_sinf(r2);
        acc = fmaf(pa.x * e2, s2, acc);
    }
    atomicAdd(&out[m * S_LEN + j], acc);
}

extern "C" void kernel_launch(void* const* d_in, const int* in_sizes, int n_in,
                              void* d_out, int out_size, void* d_ws, size_t ws_size,
                              hipStream_t stream)
{
    const float* H    = (const float*)d_in[0];   // (1, 2048, 512)
    const float* MINP = (const float*)d_in[1];   // (1,)
    const float* LNW  = (const float*)d_in[2];   // (512,)
    const float* LNB  = (const float*)d_in[3];   // (512,)
    const float* W    = (const float*)d_in[4];   // (512, 117)
    const float* B    = (const float*)d_in[5];   // (117,)
    float* out = (float*)d_out;                  // (13, 2048)

    char* ws = (char*)d_ws;
    float*  P     = (float*)ws;                                   // 2048*117*4 = 958464 B
    float2* stats = (float2*)(ws + 958464);                       // 16384 B
    float4* PARL  = (float4*)(ws + 958464 + 16384);               // 2048*13*16 = 425984 B
    float4* PARA  = (float4*)(ws + 958464 + 16384 + 425984);      // 425984 B

    hipMemsetAsync(P, 0, S_LEN * NCOL * sizeof(float), stream);
    stats_kernel<<<512, 256, 0, stream>>>(H, stats);
    proj_kernel<<<dim3(32, 8), 256, 0, stream>>>(H, stats, LNW, LNB, W, P);
    transform_kernel<<<(S_LEN * NIMU + 255) / 256, 256, 0, stream>>>(P, B, MINP, PARL, PARA, out);
    main_kernel<<<dim3(8, 8, NIMU), 256, 0, stream>>>(PARL, PARA, out);
}

// Round 2
// 144.143 us; speedup vs baseline: 1.0893x; 1.0893x over previous
//
#include <hip/hip_runtime.h>
#include <math.h>

#define S_LEN 2048
#define D_MODEL 512
#define NIMU 13
#define NPAR 9
#define NCOL 117           // 13*9
#define PCHUNK (S_LEN * NCOL)   // elements per K-partial chunk

static __device__ __forceinline__ float softplus_f(float x) {
    return (x > 20.f) ? x : log1pf(expf(x));
}

// ---------------- kernel 1: per-row layernorm stats ----------------
__global__ __launch_bounds__(256) void stats_kernel(const float* __restrict__ H,
                                                    float2* __restrict__ stats) {
    int wave = threadIdx.x >> 6;
    int lane = threadIdx.x & 63;
    int row = blockIdx.x * 4 + wave;
    if (row >= S_LEN) return;
    const float* hr = H + row * D_MODEL;
    float4 a = *(const float4*)&hr[lane * 4];
    float4 b = *(const float4*)&hr[256 + lane * 4];
    float sum = a.x + a.y + a.z + a.w + b.x + b.y + b.z + b.w;
    #pragma unroll
    for (int off = 32; off; off >>= 1) sum += __shfl_down(sum, off);
    sum = __shfl(sum, 0);
    float mu = sum * (1.f / 512.f);
    float vs = 0.f;
    vs += (a.x - mu) * (a.x - mu); vs += (a.y - mu) * (a.y - mu);
    vs += (a.z - mu) * (a.z - mu); vs += (a.w - mu) * (a.w - mu);
    vs += (b.x - mu) * (b.x - mu); vs += (b.y - mu) * (b.y - mu);
    vs += (b.z - mu) * (b.z - mu); vs += (b.w - mu) * (b.w - mu);
    #pragma unroll
    for (int off = 32; off; off >>= 1) vs += __shfl_down(vs, off);
    if (lane == 0) {
        float var = vs * (1.f / 512.f);
        float rstd = 1.0f / sqrtf(var + 1e-5f);
        stats[row] = make_float2(mu, rstd);
    }
}

// ---------------- kernel 2: projection GEMM ----------------
// grid (64 row-tiles of 32, 8 k-chunks of 64); block 256.
// ATOMIC=0: write per-chunk partials Pout[blockIdx.y][row][col] (plain stores)
// ATOMIC=1: atomicAdd into single P (fallback when ws too small)
template <int ATOMIC>
__global__ __launch_bounds__(256) void proj_kernel(
    const float* __restrict__ H, const float2* __restrict__ stats,
    const float* __restrict__ lnw, const float* __restrict__ lnb,
    const float* __restrict__ W, float* __restrict__ Pout)
{
    __shared__ float Xs[32][64];     // [row][k]
    __shared__ float Ws[64][128];    // [k][col], zero-padded cols
    int tid = threadIdx.x;
    int row0 = blockIdx.x * 32;
    int k0 = blockIdx.y * 64;

    {   // stage normalized X tile: thread -> row tid>>3, k-octet (tid&7)*8
        int r = tid >> 3;
        int k = (tid & 7) * 8;
        int row = row0 + r;
        float2 st = stats[row];
        #pragma unroll
        for (int h = 0; h < 2; ++h) {
            float4 h4 = *(const float4*)&H[row * D_MODEL + k0 + k + h * 4];
            float4 wv = *(const float4*)&lnw[k0 + k + h * 4];
            float4 bv = *(const float4*)&lnb[k0 + k + h * 4];
            Xs[r][k + h * 4 + 0] = (h4.x - st.x) * st.y * wv.x + bv.x;
            Xs[r][k + h * 4 + 1] = (h4.y - st.x) * st.y * wv.y + bv.y;
            Xs[r][k + h * 4 + 2] = (h4.z - st.x) * st.y * wv.z + bv.z;
            Xs[r][k + h * 4 + 3] = (h4.w - st.x) * st.y * wv.w + bv.w;
        }
    }
    // stage W tile (64 x 117 -> 64 x 128 zero-padded)
    #pragma unroll
    for (int it = 0; it < 32; ++it) {
        int idx = tid + it * 256;
        int k = idx >> 7;
        int c = idx & 127;
        Ws[k][c] = (c < NCOL) ? W[(k0 + k) * NCOL + c] : 0.f;
    }
    __syncthreads();

    int cg = tid & 31;   // cols cg*4 .. cg*4+3
    int rr = tid >> 5;   // rows rr + 8*q
    float acc[4][4];
    #pragma unroll
    for (int q = 0; q < 4; ++q)
        for (int u = 0; u < 4; ++u) acc[q][u] = 0.f;

    #pragma unroll 4
    for (int kb = 0; kb < 16; ++kb) {
        float4 w0 = *(float4*)&Ws[kb * 4 + 0][cg * 4];
        float4 w1 = *(float4*)&Ws[kb * 4 + 1][cg * 4];
        float4 w2 = *(float4*)&Ws[kb * 4 + 2][cg * 4];
        float4 w3 = *(float4*)&Ws[kb * 4 + 3][cg * 4];
        #pragma unroll
        for (int q = 0; q < 4; ++q) {
            float4 a = *(float4*)&Xs[rr + 8 * q][kb * 4];
            acc[q][0] = fmaf(a.w, w3.x, fmaf(a.z, w2.x, fmaf(a.y, w1.x, fmaf(a.x, w0.x, acc[q][0]))));
            acc[q][1] = fmaf(a.w, w3.y, fmaf(a.z, w2.y, fmaf(a.y, w1.y, fmaf(a.x, w0.y, acc[q][1]))));
            acc[q][2] = fmaf(a.w, w3.z, fmaf(a.z, w2.z, fmaf(a.y, w1.z, fmaf(a.x, w0.z, acc[q][2]))));
            acc[q][3] = fmaf(a.w, w3.w, fmaf(a.z, w2.w, fmaf(a.y, w1.w, fmaf(a.x, w0.w, acc[q][3]))));
        }
    }

    float* Pk = ATOMIC ? Pout : (Pout + blockIdx.y * PCHUNK);
    #pragma unroll
    for (int q = 0; q < 4; ++q) {
        int row = row0 + rr + 8 * q;
        #pragma unroll
        for (int u = 0; u < 4; ++u) {
            int c = cg * 4 + u;
            if (c < NCOL) {
                if (ATOMIC) atomicAdd(&Pk[row * NCOL + c], acc[q][u]);
                else        Pk[row * NCOL + c] = acc[q][u];
            }
        }
    }
}

// ---------------- kernel 3: K-partial reduce + param transform + out init ----------------
__global__ __launch_bounds__(256) void transform_kernel(
    const float* __restrict__ Pp, int nkc,
    const float* __restrict__ bias, const float* __restrict__ minp,
    float4* __restrict__ PARL, float4* __restrict__ PARA,
    float* __restrict__ out)
{
    int t = blockIdx.x * 256 + threadIdx.x;
    if (t >= S_LEN * NIMU) return;
    int s = t / NIMU;
    int m = t - s * NIMU;
    float pv[9];
    #pragma unroll
    for (int pp = 0; pp < 9; ++pp) {
        float v = bias[pp * NIMU + m];
        for (int kc = 0; kc < nkc; ++kc)
            v += Pp[kc * PCHUNK + s * NCOL + pp * NIMU + m];
        pv[pp] = v;
    }

    const float LOG2E = 1.4426950408889634f;
    const float INV2PI = 0.15915494309189535f;
    {   // linear oscillator
        float d = sqrtf(pv[1] * pv[1] + 1e-5f);
        float kk = d * d * 0.25f + softplus_f(pv[0]);
        float om = 0.5f * sqrtf(fmaxf(4.f * kk - d * d, 0.f));
        PARL[m * S_LEN + s] = make_float4(pv[4], -0.5f * d * LOG2E, om * INV2PI, pv[6] * INV2PI);
    }
    {   // angular oscillator
        float d = sqrtf(pv[3] * pv[3] + 1e-5f);
        float kk = d * d * 0.25f + softplus_f(pv[2]);
        float om = 0.5f * sqrtf(fmaxf(4.f * kk - d * d, 0.f));
        PARA[m * S_LEN + s] = make_float4(pv[5], -0.5f * d * LOG2E, om * INV2PI, pv[7] * INV2PI);
    }
    out[m * S_LEN + s] = minp[0] + pv[8];
}

// ---------------- kernel 4: triangular damped-sinusoid sum ----------------
__global__ __launch_bounds__(256) void main_kernel(
    const float4* __restrict__ PARL, const float4* __restrict__ PARA,
    float* __restrict__ out)
{
    int jt = blockIdx.x, ic = blockIdx.y, m = blockIdx.z;
    if (ic > jt) return;
    __shared__ float4 PL[256];
    __shared__ float4 PA[256];
    int tid = threadIdx.x;
    int i0 = ic * 256;
    PL[tid] = PARL[m * S_LEN + i0 + tid];
    PA[tid] = PARA[m * S_LEN + i0 + tid];
    __syncthreads();

    int j = jt * 256 + tid;
    float jf = (float)j;
    float acc = 0.f;
    int iimax = min(255, j - i0);
    for (int ii = 0; ii <= iimax; ++ii) {
        float dtf = jf - (float)(i0 + ii);
        float4 pl = PL[ii];
        float e1 = __builtin_amdgcn_exp2f(dtf * pl.y);
        float r1 = fmaf(dtf, pl.z, pl.w);
        r1 -= floorf(r1);
        float s1 = __builtin_amdgcn_sinf(r1);
        acc = fmaf(pl.x * e1, s1, acc);
        float4 pa = PA[ii];
        float e2 = __builtin_amdgcn_exp2f(dtf * pa.y);
        float r2 = fmaf(dtf, pa.z, pa.w);
        r2 -= floorf(r2);
        float s2 = __builtin_amdgcn_sinf(r2);
        acc = fmaf(pa.x * e2, s2, acc);
    }
    atomicAdd(&out[m * S_LEN + j], acc);
}

extern "C" void kernel_launch(void* const* d_in, const int* in_sizes, int n_in,
                              void* d_out, int out_size, void* d_ws, size_t ws_size,
                              hipStream_t stream)
{
    const float* H    = (const float*)d_in[0];
    const float* MINP = (const float*)d_in[1];
    const float* LNW  = (const float*)d_in[2];
    const float* LNB  = (const float*)d_in[3];
    const float* W    = (const float*)d_in[4];
    const float* B    = (const float*)d_in[5];
    float* out = (float*)d_out;

    const size_t PSZ   = (size_t)PCHUNK * sizeof(float);  // 958464
    const size_t STSZ  = S_LEN * sizeof(float2);          // 16384
    const size_t PARSZ = (size_t)S_LEN * NIMU * sizeof(float4); // 425984
    const size_t need8 = 8 * PSZ + STSZ + 2 * PARSZ;      // ~8.14 MB

    char* ws = (char*)d_ws;
    if (ws_size >= need8) {
        // fast path: 8 K-partials, no atomics, no memset
        float*  Pp    = (float*)ws;
        float2* stats = (float2*)(ws + 8 * PSZ);
        float4* PARL  = (float4*)(ws + 8 * PSZ + STSZ);
        float4* PARA  = (float4*)(ws + 8 * PSZ + STSZ + PARSZ);
        stats_kernel<<<512, 256, 0, stream>>>(H, stats);
        proj_kernel<0><<<dim3(64, 8), 256, 0, stream>>>(H, stats, LNW, LNB, W, Pp);
        transform_kernel<<<(S_LEN * NIMU + 255) / 256, 256, 0, stream>>>(Pp, 8, B, MINP, PARL, PARA, out);
        main_kernel<<<dim3(8, 8, NIMU), 256, 0, stream>>>(PARL, PARA, out);
    } else {
        // fallback: atomic accumulation into single P
        float*  P     = (float*)ws;
        float2* stats = (float2*)(ws + PSZ);
        float4* PARL  = (float4*)(ws + PSZ + STSZ);
        float4* PARA  = (float4*)(ws + PSZ + STSZ + PARSZ);
        hipMemsetAsync(P, 0, PSZ, stream);
        stats_kernel<<<512, 256, 0, stream>>>(H, stats);
        proj_kernel<1><<<dim3(64, 8), 256, 0, stream>>>(H, stats, LNW, LNB, W, P);
        transform_kernel<<<(S_LEN * NIMU + 255) / 256, 256, 0, stream>>>(P, 1, B, MINP, PARL, PARA, out);
        main_kernel<<<dim3(8, 8, NIMU), 256, 0, stream>>>(PARL, PARA, out);
    }
}